// Round 6
// baseline (610.696 us; speedup 1.0000x reference)
//
#include <hip/hip_runtime.h>
#include <hip/hip_bf16.h>

#define Bz 16
#define Tz 256
#define T2z 16
#define Hz 256
#define DEPTHz 8
#define ROWSz (Bz * (Tz + 2))   // 4128 rows in flat h/c tables
#define NODESz (Bz * Tz)        // 4096 tree nodes

typedef short bf16x8 __attribute__((ext_vector_type(8)));
typedef float f32x4 __attribute__((ext_vector_type(4)));

__device__ __forceinline__ float sigmoid_(float x) { return 1.0f / (1.0f + __expf(-x)); }
__device__ __forceinline__ float tanh_(float x) {
    float e = __expf(2.0f * x);
    return 1.0f - 2.0f / (e + 1.0f);
}
__device__ __forceinline__ short f2b(float f) {
    __hip_bfloat16 h = __float2bfloat16(f);
    return *(short*)&h;
}
__device__ __forceinline__ float b2f(short s) {
    return __uint_as_float(((unsigned)(unsigned short)s) << 16);
}
__device__ __forceinline__ void gload16(const short* g, short* l) {
    __builtin_amdgcn_global_load_lds((const __attribute__((address_space(1))) void*)g,
                                     (__attribute__((address_space(3))) void*)l, 16, 0, 0);
}

// C[M,N] = A[M,K]_bf16 @ BT[N,K]^T (+bias). Output fp32 (C) or bf16 (Cb).
__global__ __launch_bounds__(256) void bgemm_k(const short* __restrict__ A,
                                               const short* __restrict__ BT,
                                               const float* __restrict__ bias,
                                               float* __restrict__ C,
                                               short* __restrict__ Cb,
                                               int K, int N) {
    __shared__ short As[64 * 32];
    __shared__ short Bs[64 * 32];
    const int tid = threadIdx.x;
    const int w = tid >> 6, lane = tid & 63;
    const int m0 = blockIdx.y * 64, n0 = blockIdx.x * 64;
    const int r16 = lane & 15, q = lane >> 4;
    f32x4 acc[4] = {};
    const short* ga = A + (size_t)(m0 + w * 16 + (lane >> 2)) * K + (lane & 3) * 8;
    const short* gb = BT + (size_t)(n0 + w * 16 + (lane >> 2)) * K + (lane & 3) * 8;
    short* la = As + w * 512;
    short* lb = Bs + w * 512;
    for (int kt = 0; kt < K; kt += 32) {
        __syncthreads();
        gload16(ga + kt, la);
        gload16(gb + kt, lb);
        __syncthreads();
        bf16x8 bfrag = *(const bf16x8*)&Bs[(w * 16 + r16) * 32 + q * 8];
#pragma unroll
        for (int i = 0; i < 4; i++) {
            bf16x8 afrag = *(const bf16x8*)&As[(i * 16 + r16) * 32 + q * 8];
            acc[i] = __builtin_amdgcn_mfma_f32_16x16x32_bf16(afrag, bfrag, acc[i], 0, 0, 0);
        }
    }
    const int col = n0 + w * 16 + r16;
    const float bv = bias ? bias[col] : 0.0f;
#pragma unroll
    for (int i = 0; i < 4; i++)
#pragma unroll
        for (int r = 0; r < 4; r++) {
            const size_t o = (size_t)(m0 + i * 16 + q * 4 + r) * N + col;
            if (Cb) Cb[o] = f2b(acc[i][r] + bv);
            else    C[o]  = acc[i][r] + bv;
        }
}

// One merged prep kernel: weight transposes + composed bias + input casts +
// pad-row table init for BOTH ping-pong tables.
__global__ __launch_bounds__(256) void prep_all_k(const float* __restrict__ Wx,
                                                  const float* __restrict__ Whp,
                                                  const float* __restrict__ Whf,
                                                  const float* __restrict__ bhf,
                                                  const float* __restrict__ Whiou,
                                                  const float* __restrict__ Wdep,
                                                  const float* __restrict__ tok,
                                                  const float* __restrict__ cdep,
                                                  short* __restrict__ WTx,
                                                  short* __restrict__ WTcat,
                                                  short* __restrict__ WThiou,
                                                  short* __restrict__ WTdep,
                                                  float* __restrict__ bias_cat,
                                                  short* __restrict__ tok_b,
                                                  short* __restrict__ cdep_b,
                                                  short* __restrict__ tabA,
                                                  short* __restrict__ tabB) {
    long e = (long)blockIdx.x * 256 + threadIdx.x;
    if (e < 262144) { int n = e >> 8, k = e & 255; WTx[e] = f2b(Wx[k * 1024 + n]); return; }
    e -= 262144;
    if (e < 131072) {
        int n = e >> 8, k = e & 255;
        WTcat[e] = f2b((n < 256) ? Whp[k * 256 + n] : Whf[k * 256 + (n - 256)]);
        return;
    }
    e -= 131072;
    if (e < 196608) { int n = e >> 8, k = e & 255; WThiou[e] = f2b(Whiou[k * 768 + n]); return; }
    e -= 196608;
    if (e < 16384) { int n = e >> 6, k = e & 63; WTdep[e] = f2b(Wdep[k * 256 + n]); return; }
    e -= 16384;
    if (e < 512) { bias_cat[e] = (e < 256) ? 0.0f : bhf[e - 256]; return; }
    e -= 512;
    if (e < 262144) {  // tok cast, float4 units
        float4 v = ((const float4*)tok)[e];
        short4 o; o.x = f2b(v.x); o.y = f2b(v.y); o.z = f2b(v.z); o.w = f2b(v.w);
        ((short4*)tok_b)[e] = o;
        return;
    }
    e -= 262144;
    if (e < 1048576) {  // cdep cast, float4 units
        float4 v = ((const float4*)cdep)[e];
        short4 o; o.x = f2b(v.x); o.y = f2b(v.y); o.z = f2b(v.z); o.w = f2b(v.w);
        ((short4*)cdep_b)[e] = o;
        return;
    }
    e -= 1048576;
    if (e < 16384) {  // 32 pad rows x 2 tables: [ph=0 | pf=b_hf | rh=0 | cb=0]
        const int which = (int)(e >> 13);
        const int rr = (int)((e >> 8) & 31);
        const int c = (int)(e & 255);
        short* row = (which ? tabB : tabA) +
                     ((size_t)(rr >> 1) * (Tz + 2) + (rr & 1)) * 1024;
        row[c] = 0;
        row[256 + c] = f2b(bhf[c]);
        row[512 + c] = 0;
        row[768 + c] = 0;
    }
}
#define PREP_THREADS (262144L + 131072 + 196608 + 16384 + 512 + 262144 + 1048576 + 16384)
#define PREP_BLOCKS ((int)((PREP_THREADS + 255) / 256))

// Fused per-level kernel: 256 blocks x 1024 threads, 16 nodes/block, wave w
// owns node w end-to-end. THIS ROUND: branch-free gather — trees indices are
// always in-range and every read-table row is initialized, so ALL gather
// loads are unconditional (mask applied arithmetically: sv select, wtm =
// mask*wt, mask*cb). Straight-line dataflow lets the compiler software-
// pipeline loads across children; explicit issue order maximizes loads in
// flight (pass-2 ch0-7 issued before the butterfly, ch8-15 before their
// accumulate). VGPR headroom to 128 (4 waves/SIMD) is intentional.
__global__ __launch_bounds__(1024, 4) void level_k(const int* __restrict__ trees,
                                                   const float* __restrict__ cmask,
                                                   const short* __restrict__ tin,
                                                   const short* __restrict__ dp_b,
                                                   const float* __restrict__ attnv,
                                                   const short* __restrict__ xiou_b,
                                                   const short* __restrict__ WThiou,
                                                   const float* __restrict__ b_hiou,
                                                   const short* __restrict__ WTcat,
                                                   const float* __restrict__ biascat,
                                                   short* __restrict__ tout,
                                                   float* __restrict__ out,
                                                   int first, int last) {
    __shared__ int sidx[256];
    __shared__ float smask[256];
    __shared__ short xfL[16 * 256];     //  8 KB
    __shared__ short hjA[16 * 264];     //  8.25 KB
    __shared__ float hiouL[16 * 768];   // 48 KB
    __shared__ short htA[16 * 264];     //  8.25 KB
    const int tid = threadIdx.x;
    const int w = tid >> 6, lane = tid & 63;
    const int e0 = lane * 4;
    const int r16 = lane & 15, q = lane >> 4;
    const int p = blockIdx.x;
    const int batch = (p & 7) + 8 * ((p >> 3) >> 4);
    const int node0 = batch * 256 + ((p >> 3) & 15) * 16;
    const int b = batch, t0 = node0 & 255;
    const int gnode = node0 + w;

    float fs0 = 0.f, fs1 = 0.f, fs2 = 0.f, fs3 = 0.f;

    if (!first) {
        if (tid < 256) {
            sidx[tid] = trees[node0 * 16 + tid];
            smask[tid] = cmask[node0 * 16 + tid];
        }
        if (tid < 512) {  // stage x_f rows j=0..15 of batch b
            const int j = tid >> 5, cc = (tid & 31) * 8;
            *(int4*)(xfL + j * 256 + cc) =
                *(const int4*)(xiou_b + (size_t)(b * 256 + j) * 1024 + 768 + cc);
        }
        __syncthreads();

        const float4 av = *(const float4*)(attnv + e0);
        int roff[16]; float mkv[16];
#pragma unroll
        for (int j = 0; j < 16; j++) {
            roff[j] = sidx[w * 16 + j] << 10;   // element offset into tin
            mkv[j] = smask[w * 16 + j];
        }

        // ---- pass 1: unconditional ph+dv loads for all 16 children ----
        short4 ph[16], dv[16];
#pragma unroll
        for (int j = 0; j < 16; j++) {
            ph[j] = *(const short4*)(tin + (size_t)roff[j] + e0);
            dv[j] = *(const short4*)(dp_b + ((size_t)gnode * 16 + j) * 256 + e0);
        }
        float sv[16];
#pragma unroll
        for (int j = 0; j < 16; j++) {
            const float s = tanh_(b2f(ph[j].x) + b2f(dv[j].x)) * av.x
                          + tanh_(b2f(ph[j].y) + b2f(dv[j].y)) * av.y
                          + tanh_(b2f(ph[j].z) + b2f(dv[j].z)) * av.z
                          + tanh_(b2f(ph[j].w) + b2f(dv[j].w)) * av.w;
            sv[j] = (mkv[j] != 0.0f) ? s : -1e30f;  // -> -6.4e31 post-sum; exp -> 0
        }

        // ---- issue pass-2 loads for children 0-7 (flight covers butterfly) ----
        short4 rh[8], cbl[8], pf[8];
#pragma unroll
        for (int j = 0; j < 8; j++) {
            const short* row = tin + (size_t)roff[j];
            rh[j]  = *(const short4*)(row + 512 + e0);
            cbl[j] = *(const short4*)(row + 768 + e0);
            pf[j]  = *(const short4*)(row + 256 + e0);
        }

        // 16 independent butterfly chains, interleaved
#pragma unroll
        for (int off = 32; off > 0; off >>= 1)
#pragma unroll
            for (int j = 0; j < 16; j++) sv[j] += __shfl_xor(sv[j], off);
        // exact two-pass softmax over 16 children; denominator mask-weighted
        float mx = sv[0];
#pragma unroll
        for (int j = 1; j < 16; j++) mx = fmaxf(mx, sv[j]);
        float dsum = 0.f;
#pragma unroll
        for (int j = 0; j < 16; j++) {
            sv[j] = mkv[j] * __expf(sv[j] - mx);   // wtm: exactly 0 when masked
            dsum += sv[j];
        }
        const float inv = (dsum > 0.0f) ? 1.0f / dsum : 0.0f;  // all-masked: hj=0

        // ---- accumulate children 0-7 ----
        float hj0 = 0.f, hj1 = 0.f, hj2 = 0.f, hj3 = 0.f;
#pragma unroll
        for (int j = 0; j < 8; j++) {
            const float wt = sv[j];
            const float mk = mkv[j];
            short4 xf = *(const short4*)(xfL + j * 256 + e0);
            hj0 = fmaf(b2f(rh[j].x), wt, hj0);
            hj1 = fmaf(b2f(rh[j].y), wt, hj1);
            hj2 = fmaf(b2f(rh[j].z), wt, hj2);
            hj3 = fmaf(b2f(rh[j].w), wt, hj3);
            fs0 = fmaf(sigmoid_(b2f(xf.x) + b2f(pf[j].x)), mk * b2f(cbl[j].x), fs0);
            fs1 = fmaf(sigmoid_(b2f(xf.y) + b2f(pf[j].y)), mk * b2f(cbl[j].y), fs1);
            fs2 = fmaf(sigmoid_(b2f(xf.z) + b2f(pf[j].z)), mk * b2f(cbl[j].z), fs2);
            fs3 = fmaf(sigmoid_(b2f(xf.w) + b2f(pf[j].w)), mk * b2f(cbl[j].w), fs3);
        }
        // ---- issue + accumulate children 8-15 ----
#pragma unroll
        for (int j = 0; j < 8; j++) {
            const short* row = tin + (size_t)roff[8 + j];
            rh[j]  = *(const short4*)(row + 512 + e0);
            cbl[j] = *(const short4*)(row + 768 + e0);
            pf[j]  = *(const short4*)(row + 256 + e0);
        }
#pragma unroll
        for (int j = 0; j < 8; j++) {
            const float wt = sv[8 + j];
            const float mk = mkv[8 + j];
            short4 xf = *(const short4*)(xfL + (8 + j) * 256 + e0);
            hj0 = fmaf(b2f(rh[j].x), wt, hj0);
            hj1 = fmaf(b2f(rh[j].y), wt, hj1);
            hj2 = fmaf(b2f(rh[j].z), wt, hj2);
            hj3 = fmaf(b2f(rh[j].w), wt, hj3);
            fs0 = fmaf(sigmoid_(b2f(xf.x) + b2f(pf[j].x)), mk * b2f(cbl[j].x), fs0);
            fs1 = fmaf(sigmoid_(b2f(xf.y) + b2f(pf[j].y)), mk * b2f(cbl[j].y), fs1);
            fs2 = fmaf(sigmoid_(b2f(xf.z) + b2f(pf[j].z)), mk * b2f(cbl[j].z), fs2);
            fs3 = fmaf(sigmoid_(b2f(xf.w) + b2f(pf[j].w)), mk * b2f(cbl[j].w), fs3);
        }

        // hj (bf16, post-normalize) straight into the MFMA A-tile
        short4 hjq;
        hjq.x = f2b(hj0 * inv); hjq.y = f2b(hj1 * inv);
        hjq.z = f2b(hj2 * inv); hjq.w = f2b(hj3 * inv);
        *(short4*)(hjA + w * 264 + e0) = hjq;
        __syncthreads();

        // h_iou = hj(16x256) @ W_hiou -> hiouL; 48 N-frags / 16 waves
#pragma unroll
        for (int f = 0; f < 3; f++) {
            const int nf = w * 3 + f;
            f32x4 acc = {};
#pragma unroll
            for (int kt = 0; kt < 8; kt++) {
                bf16x8 af = *(const bf16x8*)(hjA + r16 * 264 + kt * 32 + q * 8);
                bf16x8 bf = *(const bf16x8*)(WThiou + (size_t)(nf * 16 + r16) * 256 + kt * 32 + q * 8);
                acc = __builtin_amdgcn_mfma_f32_16x16x32_bf16(af, bf, acc, 0, 0, 0);
            }
#pragma unroll
            for (int rr = 0; rr < 4; rr++)
                hiouL[(q * 4 + rr) * 768 + nf * 16 + r16] = acc[rr];
        }
        __syncthreads();
    }

    // Gates + renorm: wave w = node, lane elems e0..e0+3; fsum from registers
    {
        const short* xr = xiou_b + (size_t)gnode * 1024;
        short4 xi = *(const short4*)(xr + e0);
        short4 xo = *(const short4*)(xr + 256 + e0);
        short4 xu = *(const short4*)(xr + 512 + e0);
        float4 hi, ho, hu;
        if (!first) {
            hi = *(const float4*)(hiouL + w * 768 + e0);
            ho = *(const float4*)(hiouL + w * 768 + 256 + e0);
            hu = *(const float4*)(hiouL + w * 768 + 512 + e0);
        } else {
            hi = make_float4(0.f, 0.f, 0.f, 0.f);
            ho = hi; hu = hi;
        }
        float4 bi = *(const float4*)(b_hiou + e0);
        float4 bo = *(const float4*)(b_hiou + 256 + e0);
        float4 bu = *(const float4*)(b_hiou + 512 + e0);
        float iv[4] = { b2f(xi.x) + hi.x + bi.x, b2f(xi.y) + hi.y + bi.y,
                        b2f(xi.z) + hi.z + bi.z, b2f(xi.w) + hi.w + bi.w };
        float ov[4] = { b2f(xo.x) + ho.x + bo.x, b2f(xo.y) + ho.y + bo.y,
                        b2f(xo.z) + ho.z + bo.z, b2f(xo.w) + ho.w + bo.w };
        float uv[4] = { b2f(xu.x) + hu.x + bu.x, b2f(xu.y) + hu.y + bu.y,
                        b2f(xu.z) + hu.z + bu.z, b2f(xu.w) + hu.w + bu.w };
        float fa[4] = { fs0, fs1, fs2, fs3 };
        float hn[4], cn[4], hs = 0.0f, cs = 0.0f;
#pragma unroll
        for (int z = 0; z < 4; z++) {
            const float c = fmaf(sigmoid_(iv[z]), tanh_(uv[z]), fa[z]);
            const float h = sigmoid_(ov[z]) * tanh_(c);
            cn[z] = c; hn[z] = h;
            hs = fmaf(h, h, hs); cs = fmaf(c, c, cs);
        }
        if (last) {
            *(float4*)(out + (size_t)gnode * 256 + e0) =
                make_float4(hn[0], hn[1], hn[2], hn[3]);
            return;  // uniform across grid
        }
        // row-norm across the node's 64 lanes
#pragma unroll
        for (int off = 32; off > 0; off >>= 1) {
            hs += __shfl_xor(hs, off);
            cs += __shfl_xor(cs, off);
        }
        const float nh = sqrtf(hs), ncv = sqrtf(cs);
        const float sh = nh > 2.0f ? 2.0f / nh : 1.0f;
        const float sc = ncv > 2.0f ? 2.0f / ncv : 1.0f;
        const size_t grow = (size_t)b * (Tz + 2) + t0 + w + 2;
        short4 hb, cbv;
        hb.x = f2b(hn[0] * sh); hb.y = f2b(hn[1] * sh);
        hb.z = f2b(hn[2] * sh); hb.w = f2b(hn[3] * sh);
        cbv.x = f2b(cn[0] * sc); cbv.y = f2b(cn[1] * sc);
        cbv.z = f2b(cn[2] * sc); cbv.w = f2b(cn[3] * sc);
        *(short4*)(tout + grow * 1024 + 512 + e0) = hb;
        *(short4*)(tout + grow * 1024 + 768 + e0) = cbv;
        *(short4*)(htA + w * 264 + e0) = hb;
    }
    __syncthreads();

    // [ph|pf] = rn_h(16x256) @ [W_hproj|W_hf] + [0|b_hf] -> tout cols 0..511
#pragma unroll
    for (int f = 0; f < 2; f++) {
        const int nf = w * 2 + f;
        f32x4 acc = {};
#pragma unroll
        for (int kt = 0; kt < 8; kt++) {
            bf16x8 af = *(const bf16x8*)(htA + r16 * 264 + kt * 32 + q * 8);
            bf16x8 bf = *(const bf16x8*)(WTcat + (size_t)(nf * 16 + r16) * 256 + kt * 32 + q * 8);
            acc = __builtin_amdgcn_mfma_f32_16x16x32_bf16(af, bf, acc, 0, 0, 0);
        }
        const int col = nf * 16 + r16;
        const float bc = biascat[col];
#pragma unroll
        for (int rr = 0; rr < 4; rr++) {
            const size_t grow = (size_t)b * (Tz + 2) + t0 + q * 4 + rr + 2;
            tout[grow * 1024 + col] = f2b(acc[rr] + bc);
        }
    }
}

extern "C" void kernel_launch(void* const* d_in, const int* in_sizes, int n_in,
                              void* d_out, int out_size, void* d_ws, size_t ws_size,
                              hipStream_t stream) {
    const float* tok     = (const float*)d_in[0];
    const int*   trees   = (const int*)d_in[1];
    const float* cmask   = (const float*)d_in[2];
    const float* cdep    = (const float*)d_in[4];
    const float* W_xiouf = (const float*)d_in[5];
    const float* b_xiouf = (const float*)d_in[6];
    const float* W_hiou  = (const float*)d_in[7];
    const float* b_hiou  = (const float*)d_in[8];
    const float* W_hf    = (const float*)d_in[9];
    const float* b_hf    = (const float*)d_in[10];
    const float* W_dep   = (const float*)d_in[11];
    const float* W_hp    = (const float*)d_in[12];
    const float* W_attnv = (const float*)d_in[13];
    float* out = (float*)d_out;

    char* p = (char*)d_ws;
    auto alloc = [&](size_t bytes) { char* q = p; p += (bytes + 255) & ~255ull; return q; };
    short* tabA   = (short*)alloc((size_t)ROWSz * 1024 * 2);       // 8.5 MB packed
    short* tabB   = (short*)alloc((size_t)ROWSz * 1024 * 2);       // 8.5 MB packed
    short* dp_b   = (short*)alloc((size_t)NODESz * 16 * 256 * 2);  // 33.5 MB
    short* xiou_b = (short*)alloc((size_t)NODESz * 1024 * 2);      // 8.4 MB bf16
    short* tok_b  = (short*)alloc((size_t)NODESz * 256 * 2);
    short* cdep_b = (short*)alloc((size_t)NODESz * 16 * 64 * 2);
    short* WTx    = (short*)alloc(262144 * 2);
    short* WTcat  = (short*)alloc(131072 * 2);
    short* WThiou = (short*)alloc(196608 * 2);
    short* WTdep  = (short*)alloc(16384 * 2);
    float* biascat= (float*)alloc(512 * 4);

    prep_all_k<<<PREP_BLOCKS, 256, 0, stream>>>(W_xiouf, W_hp, W_hf, b_hf, W_hiou,
                                                W_dep, tok, cdep,
                                                WTx, WTcat, WThiou, WTdep, biascat,
                                                tok_b, cdep_b, tabA, tabB);

    // Loop-invariant GEMMs: x_iou (bf16 out incl. bias) and deprel projection
    bgemm_k<<<dim3(16, 64), 256, 0, stream>>>(tok_b, WTx, b_xiouf, nullptr, xiou_b, 256, 1024);
    bgemm_k<<<dim3(4, 1024), 256, 0, stream>>>(cdep_b, WTdep, nullptr, nullptr, dp_b, 64, 256);

    short* tabs[2] = { tabA, tabB };
    // Level 0: h=c=0 => no gathers; gates + proj only. Writes tabs[0].
    level_k<<<256, 1024, 0, stream>>>(trees, cmask, tabs[1] /*unused*/, dp_b, W_attnv,
                                      xiou_b, WThiou, b_hiou, WTcat, biascat,
                                      tabs[0], out, 1, 0);
    // Levels 1..7: level L reads tabs[(L+1)&1], writes tabs[L&1]
    for (int lvl = 1; lvl < DEPTHz; lvl++) {
        level_k<<<256, 1024, 0, stream>>>(trees, cmask, tabs[(lvl + 1) & 1], dp_b, W_attnv,
                                          xiou_b, WThiou, b_hiou, WTcat, biascat,
                                          tabs[lvl & 1], out, 0, lvl == DEPTHz - 1);
    }
}

// Round 7
// 447.082 us; speedup vs baseline: 1.3660x; 1.3660x over previous
//
#include <hip/hip_runtime.h>
#include <hip/hip_bf16.h>

#define Bz 16
#define Tz 256
#define T2z 16
#define Hz 256
#define DEPTHz 8
#define ROWSz (Bz * (Tz + 2))   // 4128 rows in flat h/c tables
#define NODESz (Bz * Tz)        // 4096 tree nodes

typedef short bf16x8 __attribute__((ext_vector_type(8)));
typedef float f32x4 __attribute__((ext_vector_type(4)));

__device__ __forceinline__ float sigmoid_(float x) { return 1.0f / (1.0f + __expf(-x)); }
__device__ __forceinline__ float tanh_(float x) {
    float e = __expf(2.0f * x);
    return 1.0f - 2.0f / (e + 1.0f);
}
__device__ __forceinline__ short f2b(float f) {
    __hip_bfloat16 h = __float2bfloat16(f);
    return *(short*)&h;
}
__device__ __forceinline__ float b2f(short s) {
    return __uint_as_float(((unsigned)(unsigned short)s) << 16);
}
__device__ __forceinline__ void gload16(const short* g, short* l) {
    __builtin_amdgcn_global_load_lds((const __attribute__((address_space(1))) void*)g,
                                     (__attribute__((address_space(3))) void*)l, 16, 0, 0);
}

// C[M,N] = A[M,K]_bf16 @ BT[N,K]^T (+bias). Output fp32 (C) or bf16 (Cb).
__global__ __launch_bounds__(256) void bgemm_k(const short* __restrict__ A,
                                               const short* __restrict__ BT,
                                               const float* __restrict__ bias,
                                               float* __restrict__ C,
                                               short* __restrict__ Cb,
                                               int K, int N) {
    __shared__ short As[64 * 32];
    __shared__ short Bs[64 * 32];
    const int tid = threadIdx.x;
    const int w = tid >> 6, lane = tid & 63;
    const int m0 = blockIdx.y * 64, n0 = blockIdx.x * 64;
    const int r16 = lane & 15, q = lane >> 4;
    f32x4 acc[4] = {};
    const short* ga = A + (size_t)(m0 + w * 16 + (lane >> 2)) * K + (lane & 3) * 8;
    const short* gb = BT + (size_t)(n0 + w * 16 + (lane >> 2)) * K + (lane & 3) * 8;
    short* la = As + w * 512;
    short* lb = Bs + w * 512;
    for (int kt = 0; kt < K; kt += 32) {
        __syncthreads();
        gload16(ga + kt, la);
        gload16(gb + kt, lb);
        __syncthreads();
        bf16x8 bfrag = *(const bf16x8*)&Bs[(w * 16 + r16) * 32 + q * 8];
#pragma unroll
        for (int i = 0; i < 4; i++) {
            bf16x8 afrag = *(const bf16x8*)&As[(i * 16 + r16) * 32 + q * 8];
            acc[i] = __builtin_amdgcn_mfma_f32_16x16x32_bf16(afrag, bfrag, acc[i], 0, 0, 0);
        }
    }
    const int col = n0 + w * 16 + r16;
    const float bv = bias ? bias[col] : 0.0f;
#pragma unroll
    for (int i = 0; i < 4; i++)
#pragma unroll
        for (int r = 0; r < 4; r++) {
            const size_t o = (size_t)(m0 + i * 16 + q * 4 + r) * N + col;
            if (Cb) Cb[o] = f2b(acc[i][r] + bv);
            else    C[o]  = acc[i][r] + bv;
        }
}

// One merged prep kernel: weight transposes + composed bias + input casts +
// pad-row table init for BOTH ping-pong tables.
__global__ __launch_bounds__(256) void prep_all_k(const float* __restrict__ Wx,
                                                  const float* __restrict__ Whp,
                                                  const float* __restrict__ Whf,
                                                  const float* __restrict__ bhf,
                                                  const float* __restrict__ Whiou,
                                                  const float* __restrict__ Wdep,
                                                  const float* __restrict__ tok,
                                                  const float* __restrict__ cdep,
                                                  short* __restrict__ WTx,
                                                  short* __restrict__ WTcat,
                                                  short* __restrict__ WThiou,
                                                  short* __restrict__ WTdep,
                                                  float* __restrict__ bias_cat,
                                                  short* __restrict__ tok_b,
                                                  short* __restrict__ cdep_b,
                                                  short* __restrict__ tabA,
                                                  short* __restrict__ tabB) {
    long e = (long)blockIdx.x * 256 + threadIdx.x;
    if (e < 262144) { int n = e >> 8, k = e & 255; WTx[e] = f2b(Wx[k * 1024 + n]); return; }
    e -= 262144;
    if (e < 131072) {
        int n = e >> 8, k = e & 255;
        WTcat[e] = f2b((n < 256) ? Whp[k * 256 + n] : Whf[k * 256 + (n - 256)]);
        return;
    }
    e -= 131072;
    if (e < 196608) { int n = e >> 8, k = e & 255; WThiou[e] = f2b(Whiou[k * 768 + n]); return; }
    e -= 196608;
    if (e < 16384) { int n = e >> 6, k = e & 63; WTdep[e] = f2b(Wdep[k * 256 + n]); return; }
    e -= 16384;
    if (e < 512) { bias_cat[e] = (e < 256) ? 0.0f : bhf[e - 256]; return; }
    e -= 512;
    if (e < 262144) {  // tok cast, float4 units
        float4 v = ((const float4*)tok)[e];
        short4 o; o.x = f2b(v.x); o.y = f2b(v.y); o.z = f2b(v.z); o.w = f2b(v.w);
        ((short4*)tok_b)[e] = o;
        return;
    }
    e -= 262144;
    if (e < 1048576) {  // cdep cast, float4 units
        float4 v = ((const float4*)cdep)[e];
        short4 o; o.x = f2b(v.x); o.y = f2b(v.y); o.z = f2b(v.z); o.w = f2b(v.w);
        ((short4*)cdep_b)[e] = o;
        return;
    }
    e -= 1048576;
    if (e < 16384) {  // 32 pad rows x 2 tables: [ph=0 | pf=b_hf | rh=0 | cb=0]
        const int which = (int)(e >> 13);
        const int rr = (int)((e >> 8) & 31);
        const int c = (int)(e & 255);
        short* row = (which ? tabB : tabA) +
                     ((size_t)(rr >> 1) * (Tz + 2) + (rr & 1)) * 1024;
        row[c] = 0;
        row[256 + c] = f2b(bhf[c]);
        row[512 + c] = 0;
        row[768 + c] = 0;
    }
}
#define PREP_THREADS (262144L + 131072 + 196608 + 16384 + 512 + 262144 + 1048576 + 16384)
#define PREP_BLOCKS ((int)((PREP_THREADS + 255) / 256))

// Fused per-level kernel: 256 blocks x 1024 threads, 16 nodes/block, wave w
// owns node w end-to-end. THIS ROUND (vs the 449-us r1 baseline):
//  (a) softmax reduction via multi-value butterfly COMPACTION: all 16 child
//      reductions in 17 shuffles (child lane&15), 1 exp, 16 bpermute
//      redistributes — replaces 96 shuffles + 96 adds + 16 exp;
//  (b) mask guards scalarized via readfirstlane (s_cbranch, no exec juggling);
//  (c) MFMA A-fragments hoisted out of the N-frag loops (-24 ds_read_b128).
// Guarded loads kept (r5 proved unconditional gathers poison L2/write-combine).
__global__ __launch_bounds__(1024, 4) void level_k(const int* __restrict__ trees,
                                                   const float* __restrict__ cmask,
                                                   const short* __restrict__ tin,
                                                   const short* __restrict__ dp_b,
                                                   const float* __restrict__ attnv,
                                                   const short* __restrict__ xiou_b,
                                                   const short* __restrict__ WThiou,
                                                   const float* __restrict__ b_hiou,
                                                   const short* __restrict__ WTcat,
                                                   const float* __restrict__ biascat,
                                                   short* __restrict__ tout,
                                                   float* __restrict__ out,
                                                   int first, int last) {
    __shared__ int sidx[256];
    __shared__ float smask[256];
    __shared__ short xfL[16 * 256];     //  8 KB
    __shared__ short hjA[16 * 264];     //  8.25 KB
    __shared__ float hiouL[16 * 768];   // 48 KB
    __shared__ short htA[16 * 264];     //  8.25 KB
    const int tid = threadIdx.x;
    const int w = tid >> 6, lane = tid & 63;
    const int e0 = lane * 4;
    const int r16 = lane & 15, q = lane >> 4;
    const int node0 = blockIdx.x * 16;
    const int b = node0 >> 8, t0 = node0 & 255;
    const int gnode = node0 + w;

    float fs0 = 0.f, fs1 = 0.f, fs2 = 0.f, fs3 = 0.f;

    if (!first) {
        if (tid < 256) {
            sidx[tid] = trees[node0 * 16 + tid];
            smask[tid] = cmask[node0 * 16 + tid];
        }
        if (tid < 512) {  // stage x_f rows j=0..15 of batch b
            const int j = tid >> 5, cc = (tid & 31) * 8;
            *(int4*)(xfL + j * 256 + cc) =
                *(const int4*)(xiou_b + (size_t)(b * 256 + j) * 1024 + 768 + cc);
        }
        __syncthreads();

        const float4 av = *(const float4*)(attnv + e0);
        float sv[16];
        // ---- pass 1: logits (ph + dv), scalar-guarded 4-wide groups ----
#pragma unroll
        for (int g = 0; g < 4; g++) {
            int idx[4], on[4];
            short4 ph[4], dv[4];
#pragma unroll
            for (int jj = 0; jj < 4; jj++) {
                idx[jj] = sidx[w * 16 + g * 4 + jj];
                on[jj] = __builtin_amdgcn_readfirstlane(
                             __float_as_int(smask[w * 16 + g * 4 + jj]));
            }
#pragma unroll
            for (int jj = 0; jj < 4; jj++) {
                if (on[jj]) {
                    ph[jj] = *(const short4*)(tin + (size_t)idx[jj] * 1024 + e0);
                    dv[jj] = *(const short4*)(dp_b + ((size_t)gnode * 16 + g * 4 + jj) * 256 + e0);
                }
            }
#pragma unroll
            for (int jj = 0; jj < 4; jj++) {
                if (on[jj]) {
                    sv[g * 4 + jj] = tanh_(b2f(ph[jj].x) + b2f(dv[jj].x)) * av.x
                                   + tanh_(b2f(ph[jj].y) + b2f(dv[jj].y)) * av.y
                                   + tanh_(b2f(ph[jj].z) + b2f(dv[jj].z)) * av.z
                                   + tanh_(b2f(ph[jj].w) + b2f(dv[jj].w)) * av.w;
                } else {
                    sv[g * 4 + jj] = -1e30f;  // -> -6.4e31 post-sum; exp -> 0
                }
            }
        }
        // ---- compaction reduce: 16 child sums in 17 shuffles ----
        // After rounds m=1,2,4,8: lane l holds child (l&15)'s 16-group total.
#pragma unroll
        for (int j = 0; j < 8; j++) {
            const float lo = sv[2 * j], hi = sv[2 * j + 1];
            const float send = (lane & 1) ? lo : hi;
            const float keep = (lane & 1) ? hi : lo;
            sv[j] = keep + __shfl_xor(send, 1);
        }
#pragma unroll
        for (int j = 0; j < 4; j++) {
            const float lo = sv[2 * j], hi = sv[2 * j + 1];
            const float send = (lane & 2) ? lo : hi;
            const float keep = (lane & 2) ? hi : lo;
            sv[j] = keep + __shfl_xor(send, 2);
        }
#pragma unroll
        for (int j = 0; j < 2; j++) {
            const float lo = sv[2 * j], hi = sv[2 * j + 1];
            const float send = (lane & 4) ? lo : hi;
            const float keep = (lane & 4) ? hi : lo;
            sv[j] = keep + __shfl_xor(send, 4);
        }
        float t;
        {
            const float lo = sv[0], hi = sv[1];
            const float send = (lane & 8) ? lo : hi;
            const float keep = (lane & 8) ? hi : lo;
            t = keep + __shfl_xor(send, 8);
        }
        t += __shfl_xor(t, 16);
        t += __shfl_xor(t, 32);   // t = full logit for child (lane&15)
        // group-max, single exp, group-sum
        float mx = t;
        mx = fmaxf(mx, __shfl_xor(mx, 1));
        mx = fmaxf(mx, __shfl_xor(mx, 2));
        mx = fmaxf(mx, __shfl_xor(mx, 4));
        mx = fmaxf(mx, __shfl_xor(mx, 8));
        const float mkc = smask[w * 16 + (lane & 15)];
        const float wtc = mkc * __expf(t - mx);   // masked child -> exactly 0
        float dsum = wtc;
        dsum += __shfl_xor(dsum, 1);
        dsum += __shfl_xor(dsum, 2);
        dsum += __shfl_xor(dsum, 4);
        dsum += __shfl_xor(dsum, 8);
        const float inv = (dsum > 0.0f) ? 1.0f / dsum : 0.0f;  // all-masked: hj=0
        // redistribute: wt[j] for all lanes
        float wt[16];
        const int gb = lane & 48;
#pragma unroll
        for (int j = 0; j < 16; j++) wt[j] = __shfl(wtc, gb | j);

        // ---- pass 2: accumulate hj (softmax-weighted rh) + fsum ----
        float hj0 = 0.f, hj1 = 0.f, hj2 = 0.f, hj3 = 0.f;
#pragma unroll
        for (int g = 0; g < 4; g++) {
            int idx[4], on[4];
            short4 rh[4], cbl[4], pf[4];
#pragma unroll
            for (int jj = 0; jj < 4; jj++) {
                idx[jj] = sidx[w * 16 + g * 4 + jj];
                on[jj] = __builtin_amdgcn_readfirstlane(
                             __float_as_int(smask[w * 16 + g * 4 + jj]));
            }
#pragma unroll
            for (int jj = 0; jj < 4; jj++) {
                if (on[jj]) {
                    const short* row = tin + (size_t)idx[jj] * 1024;
                    rh[jj]  = *(const short4*)(row + 512 + e0);
                    cbl[jj] = *(const short4*)(row + 768 + e0);
                    pf[jj]  = *(const short4*)(row + 256 + e0);
                }
            }
#pragma unroll
            for (int jj = 0; jj < 4; jj++) {
                if (on[jj]) {
                    const float wtj = wt[g * 4 + jj];
                    short4 xf = *(const short4*)(xfL + (g * 4 + jj) * 256 + e0);
                    hj0 = fmaf(b2f(rh[jj].x), wtj, hj0);
                    hj1 = fmaf(b2f(rh[jj].y), wtj, hj1);
                    hj2 = fmaf(b2f(rh[jj].z), wtj, hj2);
                    hj3 = fmaf(b2f(rh[jj].w), wtj, hj3);
                    fs0 = fmaf(sigmoid_(b2f(xf.x) + b2f(pf[jj].x)), b2f(cbl[jj].x), fs0);
                    fs1 = fmaf(sigmoid_(b2f(xf.y) + b2f(pf[jj].y)), b2f(cbl[jj].y), fs1);
                    fs2 = fmaf(sigmoid_(b2f(xf.z) + b2f(pf[jj].z)), b2f(cbl[jj].z), fs2);
                    fs3 = fmaf(sigmoid_(b2f(xf.w) + b2f(pf[jj].w)), b2f(cbl[jj].w), fs3);
                }
            }
        }
        // hj (bf16, post-normalize) straight into the MFMA A-tile
        short4 hjq;
        hjq.x = f2b(hj0 * inv); hjq.y = f2b(hj1 * inv);
        hjq.z = f2b(hj2 * inv); hjq.w = f2b(hj3 * inv);
        *(short4*)(hjA + w * 264 + e0) = hjq;
        __syncthreads();

        // h_iou = hj(16x256) @ W_hiou -> hiouL; af hoisted across N-frags
        {
            bf16x8 af[8];
#pragma unroll
            for (int kt = 0; kt < 8; kt++)
                af[kt] = *(const bf16x8*)(hjA + r16 * 264 + kt * 32 + q * 8);
#pragma unroll
            for (int f = 0; f < 3; f++) {
                const int nf = w * 3 + f;
                f32x4 acc = {};
#pragma unroll
                for (int kt = 0; kt < 8; kt++) {
                    bf16x8 bf = *(const bf16x8*)(WThiou + (size_t)(nf * 16 + r16) * 256 + kt * 32 + q * 8);
                    acc = __builtin_amdgcn_mfma_f32_16x16x32_bf16(af[kt], bf, acc, 0, 0, 0);
                }
#pragma unroll
                for (int rr = 0; rr < 4; rr++)
                    hiouL[(q * 4 + rr) * 768 + nf * 16 + r16] = acc[rr];
            }
        }
        __syncthreads();
    }

    // Gates + renorm: wave w = node, lane elems e0..e0+3; fsum from registers
    {
        const short* xr = xiou_b + (size_t)gnode * 1024;
        short4 xi = *(const short4*)(xr + e0);
        short4 xo = *(const short4*)(xr + 256 + e0);
        short4 xu = *(const short4*)(xr + 512 + e0);
        float4 hi, ho, hu;
        if (!first) {
            hi = *(const float4*)(hiouL + w * 768 + e0);
            ho = *(const float4*)(hiouL + w * 768 + 256 + e0);
            hu = *(const float4*)(hiouL + w * 768 + 512 + e0);
        } else {
            hi = make_float4(0.f, 0.f, 0.f, 0.f);
            ho = hi; hu = hi;
        }
        float4 bi = *(const float4*)(b_hiou + e0);
        float4 bo = *(const float4*)(b_hiou + 256 + e0);
        float4 bu = *(const float4*)(b_hiou + 512 + e0);
        float iv[4] = { b2f(xi.x) + hi.x + bi.x, b2f(xi.y) + hi.y + bi.y,
                        b2f(xi.z) + hi.z + bi.z, b2f(xi.w) + hi.w + bi.w };
        float ov[4] = { b2f(xo.x) + ho.x + bo.x, b2f(xo.y) + ho.y + bo.y,
                        b2f(xo.z) + ho.z + bo.z, b2f(xo.w) + ho.w + bo.w };
        float uv[4] = { b2f(xu.x) + hu.x + bu.x, b2f(xu.y) + hu.y + bu.y,
                        b2f(xu.z) + hu.z + bu.z, b2f(xu.w) + hu.w + bu.w };
        float fa[4] = { fs0, fs1, fs2, fs3 };
        float hn[4], cn[4], hs = 0.0f, cs = 0.0f;
#pragma unroll
        for (int z = 0; z < 4; z++) {
            const float c = fmaf(sigmoid_(iv[z]), tanh_(uv[z]), fa[z]);
            const float h = sigmoid_(ov[z]) * tanh_(c);
            cn[z] = c; hn[z] = h;
            hs = fmaf(h, h, hs); cs = fmaf(c, c, cs);
        }
        if (last) {
            *(float4*)(out + (size_t)gnode * 256 + e0) =
                make_float4(hn[0], hn[1], hn[2], hn[3]);
            return;  // uniform across grid
        }
        // row-norm across the node's 64 lanes
#pragma unroll
        for (int off = 32; off > 0; off >>= 1) {
            hs += __shfl_xor(hs, off);
            cs += __shfl_xor(cs, off);
        }
        const float nh = sqrtf(hs), ncv = sqrtf(cs);
        const float sh = nh > 2.0f ? 2.0f / nh : 1.0f;
        const float sc = ncv > 2.0f ? 2.0f / ncv : 1.0f;
        const size_t grow = (size_t)b * (Tz + 2) + t0 + w + 2;
        short4 hb, cbv;
        hb.x = f2b(hn[0] * sh); hb.y = f2b(hn[1] * sh);
        hb.z = f2b(hn[2] * sh); hb.w = f2b(hn[3] * sh);
        cbv.x = f2b(cn[0] * sc); cbv.y = f2b(cn[1] * sc);
        cbv.z = f2b(cn[2] * sc); cbv.w = f2b(cn[3] * sc);
        *(short4*)(tout + grow * 1024 + 512 + e0) = hb;
        *(short4*)(tout + grow * 1024 + 768 + e0) = cbv;
        *(short4*)(htA + w * 264 + e0) = hb;
    }
    __syncthreads();

    // [ph|pf] = rn_h(16x256) @ [W_hproj|W_hf] + [0|b_hf] -> tout cols 0..511
    {
        bf16x8 af[8];
#pragma unroll
        for (int kt = 0; kt < 8; kt++)
            af[kt] = *(const bf16x8*)(htA + r16 * 264 + kt * 32 + q * 8);
#pragma unroll
        for (int f = 0; f < 2; f++) {
            const int nf = w * 2 + f;
            f32x4 acc = {};
#pragma unroll
            for (int kt = 0; kt < 8; kt++) {
                bf16x8 bf = *(const bf16x8*)(WTcat + (size_t)(nf * 16 + r16) * 256 + kt * 32 + q * 8);
                acc = __builtin_amdgcn_mfma_f32_16x16x32_bf16(af[kt], bf, acc, 0, 0, 0);
            }
            const int col = nf * 16 + r16;
            const float bc = biascat[col];
#pragma unroll
            for (int rr = 0; rr < 4; rr++) {
                const size_t grow = (size_t)b * (Tz + 2) + t0 + q * 4 + rr + 2;
                tout[grow * 1024 + col] = f2b(acc[rr] + bc);
            }
        }
    }
}

extern "C" void kernel_launch(void* const* d_in, const int* in_sizes, int n_in,
                              void* d_out, int out_size, void* d_ws, size_t ws_size,
                              hipStream_t stream) {
    const float* tok     = (const float*)d_in[0];
    const int*   trees   = (const int*)d_in[1];
    const float* cmask   = (const float*)d_in[2];
    const float* cdep    = (const float*)d_in[4];
    const float* W_xiouf = (const float*)d_in[5];
    const float* b_xiouf = (const float*)d_in[6];
    const float* W_hiou  = (const float*)d_in[7];
    const float* b_hiou  = (const float*)d_in[8];
    const float* W_hf    = (const float*)d_in[9];
    const float* b_hf    = (const float*)d_in[10];
    const float* W_dep   = (const float*)d_in[11];
    const float* W_hp    = (const float*)d_in[12];
    const float* W_attnv = (const float*)d_in[13];
    float* out = (float*)d_out;

    char* p = (char*)d_ws;
    auto alloc = [&](size_t bytes) { char* q = p; p += (bytes + 255) & ~255ull; return q; };
    short* tabA   = (short*)alloc((size_t)ROWSz * 1024 * 2);       // 8.5 MB packed
    short* tabB   = (short*)alloc((size_t)ROWSz * 1024 * 2);       // 8.5 MB packed
    short* dp_b   = (short*)alloc((size_t)NODESz * 16 * 256 * 2);  // 33.5 MB
    short* xiou_b = (short*)alloc((size_t)NODESz * 1024 * 2);      // 8.4 MB bf16
    short* tok_b  = (short*)alloc((size_t)NODESz * 256 * 2);
    short* cdep_b = (short*)alloc((size_t)NODESz * 16 * 64 * 2);
    short* WTx    = (short*)alloc(262144 * 2);
    short* WTcat  = (short*)alloc(131072 * 2);
    short* WThiou = (short*)alloc(196608 * 2);
    short* WTdep  = (short*)alloc(16384 * 2);
    float* biascat= (float*)alloc(512 * 4);

    prep_all_k<<<PREP_BLOCKS, 256, 0, stream>>>(W_xiouf, W_hp, W_hf, b_hf, W_hiou,
                                                W_dep, tok, cdep,
                                                WTx, WTcat, WThiou, WTdep, biascat,
                                                tok_b, cdep_b, tabA, tabB);

    // Loop-invariant GEMMs: x_iou (bf16 out incl. bias) and deprel projection
    bgemm_k<<<dim3(16, 64), 256, 0, stream>>>(tok_b, WTx, b_xiouf, nullptr, xiou_b, 256, 1024);
    bgemm_k<<<dim3(4, 1024), 256, 0, stream>>>(cdep_b, WTdep, nullptr, nullptr, dp_b, 64, 256);

    short* tabs[2] = { tabA, tabB };
    // Level 0: h=c=0 => no gathers; gates + proj only. Writes tabs[0].
    level_k<<<256, 1024, 0, stream>>>(trees, cmask, tabs[1] /*unused*/, dp_b, W_attnv,
                                      xiou_b, WThiou, b_hiou, WTcat, biascat,
                                      tabs[0], out, 1, 0);
    // Levels 1..7: level L reads tabs[(L+1)&1], writes tabs[L&1]
    for (int lvl = 1; lvl < DEPTHz; lvl++) {
        level_k<<<256, 1024, 0, stream>>>(trees, cmask, tabs[(lvl + 1) & 1], dp_b, W_attnv,
                                          xiou_b, WThiou, b_hiou, WTcat, biascat,
                                          tabs[lvl & 1], out, 0, lvl == DEPTHz - 1);
    }
}